// Round 1
// baseline (21.310 us; speedup 1.0000x reference)
//
#include <hip/hip_runtime.h>
#include <math.h>

#define NN 2048
#define DD 64
#define TILE 64
#define PAD 4

// 64x64 output tile per 256-thread block; each thread computes a 4x4 micro-tile.
// Direct (xi - xj)^2 accumulation in fp32 (numerically exact diagonal, no
// GEMM-identity cancellation issues). LDS: xi row-major, xj transposed, both
// padded +4 floats to keep 16B alignment while breaking 64-float bank stride.
__global__ __launch_bounds__(256, 4) void cdist_tile(const float* __restrict__ x,
                                                     float* __restrict__ out) {
    __shared__ float xi[TILE][DD + PAD];     // [row i][d]
    __shared__ float xjt[DD][TILE + PAD];    // [d][row j]

    const int tid = threadIdx.x;
    const int tx = tid & 15;   // j-group (4 cols each)
    const int ty = tid >> 4;   // i-group (4 rows each)
    const int bi = blockIdx.y * TILE;
    const int bj = blockIdx.x * TILE;

    // ---- stage A panel: rows [bi, bi+64) of x, row-major ----
    {
        const float4* src = (const float4*)(x + (size_t)bi * DD);
        #pragma unroll
        for (int k = 0; k < 4; ++k) {
            int idx = tid + k * 256;          // float4 index within 64x16 panel
            int row = idx >> 4;
            int c4  = (idx & 15) << 2;
            *(float4*)(&xi[row][c4]) = src[idx];
        }
    }
    // ---- stage B panel: rows [bj, bj+64) of x, transposed to [d][j] ----
    {
        const float4* src = (const float4*)(x + (size_t)bj * DD);
        #pragma unroll
        for (int k = 0; k < 4; ++k) {
            int idx = tid + k * 256;
            int row = idx >> 4;
            int c4  = (idx & 15) << 2;
            float4 v = src[idx];
            xjt[c4 + 0][row] = v.x;
            xjt[c4 + 1][row] = v.y;
            xjt[c4 + 2][row] = v.z;
            xjt[c4 + 3][row] = v.w;
        }
    }
    __syncthreads();

    float acc[4][4] = {{0.f}};

    #pragma unroll 4
    for (int d = 0; d < DD; ++d) {
        float a[4];
        #pragma unroll
        for (int r = 0; r < 4; ++r) a[r] = xi[ty * 4 + r][d];   // broadcast reads
        float4 bv = *(const float4*)(&xjt[d][tx * 4]);          // ds_read_b128
        float b[4] = {bv.x, bv.y, bv.z, bv.w};
        #pragma unroll
        for (int r = 0; r < 4; ++r) {
            #pragma unroll
            for (int c = 0; c < 4; ++c) {
                float df = a[r] - b[c];
                acc[r][c] = fmaf(df, df, acc[r][c]);
            }
        }
    }

    // ---- epilogue: sqrt + coalesced float4 stores ----
    #pragma unroll
    for (int r = 0; r < 4; ++r) {
        int i = bi + ty * 4 + r;
        float4 o;
        o.x = sqrtf(acc[r][0]);
        o.y = sqrtf(acc[r][1]);
        o.z = sqrtf(acc[r][2]);
        o.w = sqrtf(acc[r][3]);
        *(float4*)(out + (size_t)i * NN + bj + tx * 4) = o;
    }
}

extern "C" void kernel_launch(void* const* d_in, const int* in_sizes, int n_in,
                              void* d_out, int out_size, void* d_ws, size_t ws_size,
                              hipStream_t stream) {
    const float* x = (const float*)d_in[0];
    float* out = (float*)d_out;
    dim3 grid(NN / TILE, NN / TILE);   // 32 x 32 = 1024 blocks
    cdist_tile<<<grid, dim3(256), 0, stream>>>(x, out);
}

// Round 4
// 15.391 us; speedup vs baseline: 1.3846x; 1.3846x over previous
//
#include <hip/hip_runtime.h>
#include <math.h>

#define NN 2048
#define DD 64
#define BT 128            // block tile edge (M and N)
#define LDK (128 + 8)     // K=128 bf16 (= [hi|lo]) + 16B pad (row stride 17 quads -> bank-spread)

typedef short short8 __attribute__((ext_vector_type(8)));   // 8 bf16 patterns (4 VGPR)
typedef float f32x4 __attribute__((ext_vector_type(4)));
typedef unsigned short us4 __attribute__((ext_vector_type(4)));

__device__ inline unsigned short f2bf(float f) {            // fp32 -> bf16 RNE
    unsigned u = __float_as_uint(f);
    return (unsigned short)((u + 0x7FFFu + ((u >> 16) & 1u)) >> 16);
}
__device__ inline float bf2f(unsigned short b) {
    return __uint_as_float(((unsigned)b) << 16);
}

// d2(i,j) = n_i + n_j - 2*G_ij,  G = C·C^T, C = [hi|lo] bf16 split of x (K=128).
// Verified (R3 self-calibration == presumed m89 layout): C/D col=lane&15,
// row=(lane>>4)*4+reg. The [hi|lo] split drops the 2*hi*lo cross term, which
// only matters on the diagonal (reference is exactly 0 there) -> diagonal is
// written as exact 0. Off-diagonal split error <= ~0.03 in d (threshold 0.33).
__global__ __launch_bounds__(256) void cdist_mfma(const float* __restrict__ x,
                                                  float* __restrict__ out) {
    __shared__ unsigned short CA[BT][LDK];
    __shared__ unsigned short CB[BT][LDK];
    __shared__ float nrmA[BT], nrmB[BT];

    const int tid = threadIdx.x;
    const int bi = blockIdx.y * BT;
    const int bj = blockIdx.x * BT;

    // ---- stage + split both panels: 128 rows x 64 fp32 -> [hi(64)|lo(64)] bf16 ----
    #pragma unroll
    for (int p = 0; p < 2; ++p) {
        const float4* src = (const float4*)(x + (size_t)(p ? bj : bi) * DD);
        unsigned short (*C)[LDK] = p ? CB : CA;
        #pragma unroll
        for (int s = 0; s < 8; ++s) {
            int idx = tid + s * 256;
            int row = idx >> 4;
            int c4  = (idx & 15) << 2;
            float4 v = src[idx];
            unsigned short h0 = f2bf(v.x), h1 = f2bf(v.y), h2 = f2bf(v.z), h3 = f2bf(v.w);
            us4 hv = {h0, h1, h2, h3};
            us4 lv = {f2bf(v.x - bf2f(h0)), f2bf(v.y - bf2f(h1)),
                      f2bf(v.z - bf2f(h2)), f2bf(v.w - bf2f(h3))};
            *(us4*)(&C[row][c4])      = hv;
            *(us4*)(&C[row][64 + c4]) = lv;
        }
    }

    // ---- fp32 row norms (x is L2-resident) ----
    {
        int r = tid & 127;
        const float4* row = (const float4*)(x + (size_t)((tid < 128 ? bi : bj) + r) * DD);
        float s = 0.f;
        #pragma unroll
        for (int q = 0; q < 16; ++q) {
            float4 v = row[q];
            s = fmaf(v.x, v.x, s); s = fmaf(v.y, v.y, s);
            s = fmaf(v.z, v.z, s); s = fmaf(v.w, v.w, s);
        }
        if (tid < 128) nrmA[r] = s; else nrmB[r] = s;
    }
    __syncthreads();

    const int lane = tid & 63;
    const int wid  = tid >> 6;
    const int wm = wid >> 1, wn = wid & 1;
    const int lr = lane & 15;             // A-row / B-col within 16-frag
    const int lk = (lane >> 4) * 8;       // k-base within 32-frag

    // ---- gram: each wave owns 64x64, 4x4 fragments, K=128 ----
    f32x4 acc[4][4] = {};
    #pragma unroll
    for (int ks = 0; ks < 4; ++ks) {
        const int k = ks * 32 + lk;
        short8 af[4], bfr[4];
        #pragma unroll
        for (int m = 0; m < 4; ++m)
            af[m] = *(const short8*)(&CA[wm * 64 + m * 16 + lr][k]);
        #pragma unroll
        for (int n = 0; n < 4; ++n)
            bfr[n] = *(const short8*)(&CB[wn * 64 + n * 16 + lr][k]);
        #pragma unroll
        for (int m = 0; m < 4; ++m)
            #pragma unroll
            for (int n = 0; n < 4; ++n)
                acc[m][n] = __builtin_amdgcn_mfma_f32_16x16x32_bf16(af[m], bfr[n], acc[m][n], 0, 0, 0);
    }

    // ---- epilogue: d = sqrt(relu(nA + nB - 2G)); exact 0 on the diagonal ----
    #pragma unroll
    for (int m = 0; m < 4; ++m) {
        #pragma unroll
        for (int g = 0; g < 4; ++g) {
            const int row = wm * 64 + m * 16 + (lane >> 4) * 4 + g;   // C/D row
            const float na = nrmA[row];
            const int gi = bi + row;
            float* orow = out + (size_t)gi * NN + bj;
            #pragma unroll
            for (int n = 0; n < 4; ++n) {
                const int col = wn * 64 + n * 16 + lr;                 // C/D col
                const int gj = bj + col;
                float v = na + nrmB[col] - 2.f * acc[m][n][g];
                float d = sqrtf(fmaxf(v, 0.f));
                orow[col] = (gi == gj) ? 0.f : d;
            }
        }
    }
}

extern "C" void kernel_launch(void* const* d_in, const int* in_sizes, int n_in,
                              void* d_out, int out_size, void* d_ws, size_t ws_size,
                              hipStream_t stream) {
    const float* x = (const float*)d_in[0];
    float* out = (float*)d_out;
    dim3 grid(NN / BT, NN / BT);   // 16 x 16 = 256 blocks
    cdist_mfma<<<grid, dim3(256), 0, stream>>>(x, out);
}

// Round 5
// 14.951 us; speedup vs baseline: 1.4253x; 1.0295x over previous
//
#include <hip/hip_runtime.h>
#include <math.h>

#define NN 2048
#define DD 64
#define BT 64             // block tile edge: 64x64 -> 1024 blocks = 4/CU (16 waves/CU)
#define LDK (128 + 8)     // K=128 bf16 ([hi|lo]) + 16B pad

typedef short short8 __attribute__((ext_vector_type(8)));   // 8 bf16 patterns (4 VGPR)
typedef float f32x4 __attribute__((ext_vector_type(4)));
typedef unsigned short us4 __attribute__((ext_vector_type(4)));

__device__ inline unsigned short f2bf(float f) {            // fp32 -> bf16 RNE
    unsigned u = __float_as_uint(f);
    return (unsigned short)((u + 0x7FFFu + ((u >> 16) & 1u)) >> 16);
}
__device__ inline float bf2f(unsigned short b) {
    return __uint_as_float(((unsigned)b) << 16);
}

// d2(i,j) = n_i + n_j - 2*G_ij,  G = C·C^T, C = [hi|lo] bf16 split of x (K=128).
// Layout verified in R3/R4 (C/D: col=lane&15, row=(lane>>4)*4+reg). Diagonal
// written as exact 0 (reference is identically 0; split drops 2*hi*lo there).
// R5 change: 64x64 tiles -> 4 blocks/CU for latency hiding (R4 was 1/CU).
__global__ __launch_bounds__(256, 4) void cdist_mfma(const float* __restrict__ x,
                                                     float* __restrict__ out) {
    __shared__ unsigned short CA[BT][LDK];
    __shared__ unsigned short CB[BT][LDK];
    __shared__ float nrmA[BT], nrmB[BT];

    const int tid = threadIdx.x;
    const int bi = blockIdx.y * BT;
    const int bj = blockIdx.x * BT;

    // ---- stage + split both panels: 64 rows x 64 fp32 -> [hi(64)|lo(64)] bf16 ----
    #pragma unroll
    for (int p = 0; p < 2; ++p) {
        const float4* src = (const float4*)(x + (size_t)(p ? bj : bi) * DD);
        unsigned short (*C)[LDK] = p ? CB : CA;
        #pragma unroll
        for (int s = 0; s < 4; ++s) {
            int idx = tid + s * 256;        // float4 index in [0, 1024)
            int row = idx >> 4;             // 16 float4 per row
            int c4  = (idx & 15) << 2;
            float4 v = src[idx];
            unsigned short h0 = f2bf(v.x), h1 = f2bf(v.y), h2 = f2bf(v.z), h3 = f2bf(v.w);
            us4 hv = {h0, h1, h2, h3};
            us4 lv = {f2bf(v.x - bf2f(h0)), f2bf(v.y - bf2f(h1)),
                      f2bf(v.z - bf2f(h2)), f2bf(v.w - bf2f(h3))};
            *(us4*)(&C[row][c4])      = hv;
            *(us4*)(&C[row][64 + c4]) = lv;
        }
    }

    // ---- fp32 row norms (x is L2-resident); threads 0..127 cover 128 rows ----
    if (tid < 128) {
        int r = tid & 63;
        const float4* row = (const float4*)(x + (size_t)((tid < 64 ? bi : bj) + r) * DD);
        float s = 0.f;
        #pragma unroll
        for (int q = 0; q < 16; ++q) {
            float4 v = row[q];
            s = fmaf(v.x, v.x, s); s = fmaf(v.y, v.y, s);
            s = fmaf(v.z, v.z, s); s = fmaf(v.w, v.w, s);
        }
        if (tid < 64) nrmA[r] = s; else nrmB[r] = s;
    }
    __syncthreads();

    const int lane = tid & 63;
    const int wid  = tid >> 6;
    const int wm = wid >> 1, wn = wid & 1;   // 2x2 wave grid, each 32x32
    const int lr = lane & 15;                // A-row / B-col within 16-frag
    const int lk = (lane >> 4) * 8;          // k-base within 32-frag

    // ---- gram: each wave owns 32x32 = 2x2 fragments, K=128 ----
    f32x4 acc[2][2] = {};
    #pragma unroll
    for (int ks = 0; ks < 4; ++ks) {
        const int k = ks * 32 + lk;
        short8 af[2], bfr[2];
        #pragma unroll
        for (int m = 0; m < 2; ++m)
            af[m] = *(const short8*)(&CA[wm * 32 + m * 16 + lr][k]);
        #pragma unroll
        for (int n = 0; n < 2; ++n)
            bfr[n] = *(const short8*)(&CB[wn * 32 + n * 16 + lr][k]);
        #pragma unroll
        for (int m = 0; m < 2; ++m)
            #pragma unroll
            for (int n = 0; n < 2; ++n)
                acc[m][n] = __builtin_amdgcn_mfma_f32_16x16x32_bf16(af[m], bfr[n], acc[m][n], 0, 0, 0);
    }

    // ---- epilogue: d = sqrt(relu(nA + nB - 2G)); exact 0 on the diagonal ----
    #pragma unroll
    for (int m = 0; m < 2; ++m) {
        #pragma unroll
        for (int g = 0; g < 4; ++g) {
            const int row = wm * 32 + m * 16 + (lane >> 4) * 4 + g;   // C/D row
            const float na = nrmA[row];
            const int gi = bi + row;
            float* orow = out + (size_t)gi * NN + bj;
            #pragma unroll
            for (int n = 0; n < 2; ++n) {
                const int col = wn * 32 + n * 16 + lr;                // C/D col
                const int gj = bj + col;
                float v = na + nrmB[col] - 2.f * acc[m][n][g];
                float d = sqrtf(fmaxf(v, 0.f));
                orow[col] = (gi == gj) ? 0.f : d;
            }
        }
    }
}

extern "C" void kernel_launch(void* const* d_in, const int* in_sizes, int n_in,
                              void* d_out, int out_size, void* d_ws, size_t ws_size,
                              hipStream_t stream) {
    const float* x = (const float*)d_in[0];
    float* out = (float*)d_out;
    dim3 grid(NN / BT, NN / BT);   // 32 x 32 = 1024 blocks (4 per CU)
    cdist_mfma<<<grid, dim3(256), 0, stream>>>(x, out);
}